// Round 1
// baseline (352.641 us; speedup 1.0000x reference)
//
#include <hip/hip_runtime.h>
#include <hip/hip_bf16.h>
#include <math.h>

typedef __attribute__((ext_vector_type(8))) __bf16 bf16x8;
typedef __attribute__((ext_vector_type(4))) __bf16 bf16x4;
typedef __attribute__((ext_vector_type(2))) __bf16 bf16x2;
typedef __attribute__((ext_vector_type(4))) float  f32x4;

#define MFMA16(a,b,c) __builtin_amdgcn_mfma_f32_16x16x32_bf16((a),(b),(c),0,0,0)

__device__ __forceinline__ float wave16_max(float v){
  v = fmaxf(v, __shfl_xor(v,1));
  v = fmaxf(v, __shfl_xor(v,2));
  v = fmaxf(v, __shfl_xor(v,4));
  v = fmaxf(v, __shfl_xor(v,8));
  return v;
}
__device__ __forceinline__ float wave16_sum(float v){
  v += __shfl_xor(v,1);
  v += __shfl_xor(v,2);
  v += __shfl_xor(v,4);
  v += __shfl_xor(v,8);
  return v;
}

// ---------------------------------------------------------------------------
// Generic GEMM: C[M,N] = A[M,K] @ W[N,K]^T + bias, fp32 inputs, bf16 MFMA.
// BM=128, BN=64, BK=32, 256 threads (4 waves, 2x2), each wave 64x32.
// ---------------------------------------------------------------------------
template<bool RELU, bool BF16OUT>
__global__ __launch_bounds__(256) void gemm_bt(
    const float* __restrict__ A, const float* __restrict__ W,
    const float* __restrict__ bias, void* __restrict__ Cv,
    int M, int N, int K, int ldc, int coff)
{
  __shared__ __align__(16) __bf16 As[128][40];
  __shared__ __align__(16) __bf16 Bs[64][40];

  const int tid  = threadIdx.x;
  const int wid  = tid >> 6;
  const int lane = tid & 63;
  const int wr   = wid >> 1;      // 0..1 (row half)
  const int wc   = wid & 1;       // 0..1 (col half)
  const int lq   = lane & 15;
  const int lk8  = (lane >> 4) << 3;
  const int rb   = (lane >> 4) << 2;

  const int m0 = blockIdx.x * 128;
  const int n0 = blockIdx.y * 64;

  const int scg = (tid & 7) << 2;  // col in k-tile (0,4,..,28)
  const int sr  = tid >> 3;        // 0..31

  f32x4 acc[4][2];
  #pragma unroll
  for (int i=0;i<4;i++)
    #pragma unroll
    for (int j=0;j<2;j++) acc[i][j] = f32x4{0.f,0.f,0.f,0.f};

  for (int k0=0; k0<K; k0+=32){
    __syncthreads();
    #pragma unroll
    for (int i=0;i<4;i++){
      const int row = sr + i*32;
      const float4 a4 = *(const float4*)&A[(size_t)(m0+row)*K + k0 + scg];
      bf16x4 h; h[0]=(__bf16)a4.x; h[1]=(__bf16)a4.y; h[2]=(__bf16)a4.z; h[3]=(__bf16)a4.w;
      *(bf16x4*)&As[row][scg] = h;
    }
    #pragma unroll
    for (int i=0;i<2;i++){
      const int row = sr + i*32;
      const float4 a4 = *(const float4*)&W[(size_t)(n0+row)*K + k0 + scg];
      bf16x4 h; h[0]=(__bf16)a4.x; h[1]=(__bf16)a4.y; h[2]=(__bf16)a4.z; h[3]=(__bf16)a4.w;
      *(bf16x4*)&Bs[row][scg] = h;
    }
    __syncthreads();
    bf16x8 af[4], bfr[2];
    #pragma unroll
    for (int i=0;i<4;i++) af[i]  = *(const bf16x8*)&As[wr*64 + i*16 + lq][lk8];
    #pragma unroll
    for (int j=0;j<2;j++) bfr[j] = *(const bf16x8*)&Bs[wc*32 + j*16 + lq][lk8];
    #pragma unroll
    for (int i=0;i<4;i++)
      #pragma unroll
      for (int j=0;j<2;j++)
        acc[i][j] = MFMA16(af[i], bfr[j], acc[i][j]);
  }

  #pragma unroll
  for (int i=0;i<4;i++)
    #pragma unroll
    for (int j=0;j<2;j++){
      const int coln = n0 + wc*32 + j*16 + lq;   // global N index
      const float bv = bias ? bias[coln] : 0.f;
      #pragma unroll
      for (int r=0;r<4;r++){
        const int rowm = m0 + wr*64 + i*16 + rb + r;
        float vv = acc[i][j][r] + bv;
        if (RELU) vv = fmaxf(vv, 0.f);
        const size_t idx = (size_t)rowm*ldc + coff + coln;
        if (BF16OUT) ((__bf16*)Cv)[idx] = (__bf16)vv;
        else         ((float*)Cv)[idx]  = vv;
      }
    }
}

// ---------------------------------------------------------------------------
// qk = a + b (float4)
// ---------------------------------------------------------------------------
__global__ __launch_bounds__(256) void add_vec4(const float* __restrict__ a,
                                                const float* __restrict__ b,
                                                float* __restrict__ o, int n4)
{
  const int i = blockIdx.x*blockDim.x + threadIdx.x;
  if (i < n4){
    const float4 x = ((const float4*)a)[i];
    const float4 y = ((const float4*)b)[i];
    float4 z; z.x=x.x+y.x; z.y=x.y+y.y; z.z=x.z+y.z; z.w=x.w+y.w;
    ((float4*)o)[i] = z;
  }
}

// ---------------------------------------------------------------------------
// LN: out = LN(res + x) * g + beta   (rows x 256), 4 waves/block = 4 rows
// ---------------------------------------------------------------------------
__global__ __launch_bounds__(256) void ln_kernel(const float* __restrict__ res,
                                                 const float* __restrict__ x,
                                                 const float* __restrict__ g,
                                                 const float* __restrict__ beta,
                                                 float* __restrict__ out)
{
  const int row  = blockIdx.x*4 + (threadIdx.x >> 6);
  const int lane = threadIdx.x & 63;
  const int c = lane*4;
  const float4 rv = *(const float4*)&res[(size_t)row*256 + c];
  const float4 xv = *(const float4*)&x[(size_t)row*256 + c];
  float v0=rv.x+xv.x, v1=rv.y+xv.y, v2=rv.z+xv.z, v3=rv.w+xv.w;
  float s = v0+v1+v2+v3;
  #pragma unroll
  for (int off=1; off<64; off<<=1) s += __shfl_xor(s, off);
  const float mean = s * (1.f/256.f);
  const float d0=v0-mean, d1=v1-mean, d2=v2-mean, d3=v3-mean;
  float q = d0*d0 + d1*d1 + d2*d2 + d3*d3;
  #pragma unroll
  for (int off=1; off<64; off<<=1) q += __shfl_xor(q, off);
  const float rstd = rsqrtf(q*(1.f/256.f) + 1e-5f);
  const float4 gv = *(const float4*)&g[c];
  const float4 bv = *(const float4*)&beta[c];
  float4 ov;
  ov.x = d0*rstd*gv.x + bv.x;
  ov.y = d1*rstd*gv.y + bv.y;
  ov.z = d2*rstd*gv.z + bv.z;
  ov.w = d3*rstd*gv.w + bv.w;
  *(float4*)&out[(size_t)row*256 + c] = ov;
}

// ---------------------------------------------------------------------------
// srcs (8,256,4096) -> smat (8,4096,256)
// ---------------------------------------------------------------------------
__global__ __launch_bounds__(256) void transpose_srcs(const float* __restrict__ srcs,
                                                      float* __restrict__ smat)
{
  __shared__ float tile[32][33];
  const int tx = threadIdx.x & 31, ty = threadIdx.x >> 5;
  const int p0 = blockIdx.x * 32, c0 = blockIdx.y * 32, b = blockIdx.z;
  const float* sb = srcs + (size_t)b*256*4096;
  #pragma unroll
  for (int i=0;i<4;i++){
    const int c = c0 + ty + i*8;
    tile[ty+i*8][tx] = sb[(size_t)c*4096 + p0 + tx];
  }
  __syncthreads();
  float* ob = smat + (size_t)b*4096*256;
  #pragma unroll
  for (int i=0;i<4;i++){
    const int p = p0 + ty + i*8;
    ob[(size_t)p*256 + c0 + tx] = tile[tx][ty+i*8];
  }
}

// ---------------------------------------------------------------------------
// Flash self-attention. qkv bf16 [8192][768] (q:0-255, k:256-511, v:512-767).
// One block = (qtile of 64 rows, b, h). 4 waves x 16 q-rows. DH=32.
// ---------------------------------------------------------------------------
__global__ __launch_bounds__(256) void flash_self(const __bf16* __restrict__ qkv,
                                                  float* __restrict__ sa)
{
  const int qt = blockIdx.x;
  const int b  = blockIdx.y >> 3;
  const int h  = blockIdx.y & 7;
  const int tid  = threadIdx.x;
  const int wid  = tid >> 6;
  const int lane = tid & 63;
  const int lq   = lane & 15;
  const int lk8  = (lane >> 4) << 3;
  const int rb   = (lane >> 4) << 2;

  __shared__ __align__(16) __bf16 Vt[32][40];      // [dim][key]
  __shared__ __align__(16) __bf16 Pl[4][16][40];   // per-wave P

  const int qrow = b*1024 + qt*64 + wid*16 + lq;
  const bf16x8 qf = *(const bf16x8*)&qkv[(size_t)qrow*768 + h*32 + lk8];

  float m[4], l[4];
  f32x4 o[2];
  #pragma unroll
  for (int r=0;r<4;r++){ m[r] = -1e30f; l[r] = 0.f; }
  o[0] = f32x4{0.f,0.f,0.f,0.f};
  o[1] = f32x4{0.f,0.f,0.f,0.f};

  const int vk = tid & 31;          // key for V staging
  const int vd = (tid >> 5) << 2;   // dim group of 4
  const float scale = 0.17677669529663687f;  // 1/sqrt(32)

  for (int kc=0; kc<32; ++kc){
    const int key0 = kc*32;
    __syncthreads();  // previous PV reads of Vt done
    { // stage V^T
      const bf16x4 vv = *(const bf16x4*)&qkv[(size_t)(b*1024 + key0 + vk)*768 + 512 + h*32 + vd];
      #pragma unroll
      for (int j=0;j<4;j++) Vt[vd+j][vk] = vv[j];
    }
    // S = Q K^T (K frags straight from global in B-layout)
    const __bf16* kbase = &qkv[(size_t)(b*1024 + key0)*768 + 256 + h*32 + lk8];
    const bf16x8 kf0 = *(const bf16x8*)(kbase + (size_t)lq*768);
    const bf16x8 kf1 = *(const bf16x8*)(kbase + (size_t)(16+lq)*768);
    const f32x4 z = f32x4{0.f,0.f,0.f,0.f};
    const f32x4 s0 = MFMA16(qf, kf0, z);
    const f32x4 s1 = MFMA16(qf, kf1, z);
    // online softmax (rows spread over 16-lane groups)
    #pragma unroll
    for (int r=0;r<4;r++){
      const float a0 = s0[r]*scale, a1 = s1[r]*scale;
      const float mx = wave16_max(fmaxf(a0,a1));
      const float mn = fmaxf(m[r], mx);
      const float alpha = __expf(m[r]-mn);
      const float p0 = __expf(a0-mn);
      const float p1 = __expf(a1-mn);
      const float rs = wave16_sum(p0+p1);
      l[r] = l[r]*alpha + rs;
      o[0][r] *= alpha;
      o[1][r] *= alpha;
      m[r] = mn;
      Pl[wid][rb+r][lq]      = (__bf16)p0;
      Pl[wid][rb+r][16+lq]   = (__bf16)p1;
    }
    __syncthreads();  // Vt staged + P visible
    const bf16x8 pf  = *(const bf16x8*)&Pl[wid][lq][lk8];
    const bf16x8 vf0 = *(const bf16x8*)&Vt[lq][lk8];
    const bf16x8 vf1 = *(const bf16x8*)&Vt[16+lq][lk8];
    o[0] = MFMA16(pf, vf0, o[0]);
    o[1] = MFMA16(pf, vf1, o[1]);
  }
  #pragma unroll
  for (int nf=0;nf<2;nf++)
    #pragma unroll
    for (int r=0;r<4;r++){
      const int row = b*1024 + qt*64 + wid*16 + rb + r;
      sa[(size_t)row*256 + h*32 + nf*16 + lq] = o[nf][r] / l[r];
    }
}

// ---------------------------------------------------------------------------
// Flash cross-attention with KV-split. q bf16 (8192,256), k/v bf16 (32768,256).
// Block = (qtile 64, b, slice of 1024 keys). Writes unnormalized O + (m,l).
// ---------------------------------------------------------------------------
__global__ __launch_bounds__(256) void flash_cross(
    const __bf16* __restrict__ q, const __bf16* __restrict__ k,
    const __bf16* __restrict__ v, float* __restrict__ Opart,
    float* __restrict__ ml)
{
  const int qt = blockIdx.x;   // 0..15
  const int b  = blockIdx.y;   // 0..7
  const int sl = blockIdx.z;   // 0..3
  const int tid  = threadIdx.x;
  const int wid  = tid >> 6;
  const int lane = tid & 63;
  const int lq   = lane & 15;
  const int lk8  = (lane >> 4) << 3;
  const int rb   = (lane >> 4) << 2;

  __shared__ __align__(16) __bf16 Ks[32][264];     // [key][dim]
  __shared__ __align__(16) __bf16 Vt[256][40];     // [dim][key]
  __shared__ __align__(16) __bf16 Pl[4][16][40];

  const int qrow = b*1024 + qt*64 + wid*16 + lq;
  bf16x8 qf[8];
  #pragma unroll
  for (int ks=0; ks<8; ks++)
    qf[ks] = *(const bf16x8*)&q[(size_t)qrow*256 + ks*32 + lk8];

  float m[4], l[4];
  f32x4 o[16];
  #pragma unroll
  for (int r=0;r<4;r++){ m[r] = -1e30f; l[r] = 0.f; }
  #pragma unroll
  for (int nf=0;nf<16;nf++) o[nf] = f32x4{0.f,0.f,0.f,0.f};

  const int kkey = tid >> 3;         // 0..31
  const int kg   = (tid & 7) << 5;   // col group of 32
  const int vkp  = (tid & 15) << 1;  // key pair base
  const int vdg  = (tid >> 4) << 4;  // dim group of 16

  for (int kc=0; kc<32; ++kc){
    const int key0 = sl*1024 + kc*32;
    __syncthreads();  // prev PV/S reads done
    { // stage K rows
      const __bf16* src = &k[(size_t)(b*4096 + key0 + kkey)*256 + kg];
      #pragma unroll
      for (int j=0;j<4;j++)
        *(bf16x8*)&Ks[kkey][kg + j*8] = *(const bf16x8*)(src + j*8);
    }
    { // stage V^T (pack 2 keys per b32 write)
      const __bf16* s0p = &v[(size_t)(b*4096 + key0 + vkp)*256 + vdg];
      const bf16x8 r0a = *(const bf16x8*)(s0p);
      const bf16x8 r0b = *(const bf16x8*)(s0p + 8);
      const bf16x8 r1a = *(const bf16x8*)(s0p + 256);
      const bf16x8 r1b = *(const bf16x8*)(s0p + 264);
      #pragma unroll
      for (int d=0; d<8; d++){
        bf16x2 w2; w2.x = r0a[d]; w2.y = r1a[d];
        *(bf16x2*)&Vt[vdg + d][vkp] = w2;
      }
      #pragma unroll
      for (int d=0; d<8; d++){
        bf16x2 w2; w2.x = r0b[d]; w2.y = r1b[d];
        *(bf16x2*)&Vt[vdg + 8 + d][vkp] = w2;
      }
    }
    __syncthreads();  // tiles staged
    // S = Q K^T over full 256 dims (no scale in reference)
    f32x4 s0 = f32x4{0.f,0.f,0.f,0.f};
    f32x4 s1 = f32x4{0.f,0.f,0.f,0.f};
    #pragma unroll
    for (int ks=0; ks<8; ks++){
      const bf16x8 kf0 = *(const bf16x8*)&Ks[lq][ks*32 + lk8];
      const bf16x8 kf1 = *(const bf16x8*)&Ks[16+lq][ks*32 + lk8];
      s0 = MFMA16(qf[ks], kf0, s0);
      s1 = MFMA16(qf[ks], kf1, s1);
    }
    float alpha[4];
    #pragma unroll
    for (int r=0;r<4;r++){
      const float a0 = s0[r], a1 = s1[r];
      const float mx = wave16_max(fmaxf(a0,a1));
      const float mn = fmaxf(m[r], mx);
      alpha[r] = __expf(m[r]-mn);
      const float p0 = __expf(a0-mn);
      const float p1 = __expf(a1-mn);
      const float rs = wave16_sum(p0+p1);
      l[r] = l[r]*alpha[r] + rs;
      m[r] = mn;
      Pl[wid][rb+r][lq]    = (__bf16)p0;
      Pl[wid][rb+r][16+lq] = (__bf16)p1;
    }
    #pragma unroll
    for (int nf=0;nf<16;nf++){
      o[nf][0]*=alpha[0]; o[nf][1]*=alpha[1];
      o[nf][2]*=alpha[2]; o[nf][3]*=alpha[3];
    }
    __syncthreads();  // P visible
    const bf16x8 pf = *(const bf16x8*)&Pl[wid][lq][lk8];
    #pragma unroll
    for (int nf=0;nf<16;nf++){
      const bf16x8 vf = *(const bf16x8*)&Vt[nf*16 + lq][lk8];
      o[nf] = MFMA16(pf, vf, o[nf]);
    }
  }
  // epilogue: unnormalized O + (m,l)
  if (lq == 0){
    #pragma unroll
    for (int r=0;r<4;r++){
      const int row = b*1024 + qt*64 + wid*16 + rb + r;
      ml[(size_t)(sl*8192 + row)*2 + 0] = m[r];
      ml[(size_t)(sl*8192 + row)*2 + 1] = l[r];
    }
  }
  #pragma unroll
  for (int nf=0;nf<16;nf++)
    #pragma unroll
    for (int r=0;r<4;r++){
      const int row = b*1024 + qt*64 + wid*16 + rb + r;
      Opart[(size_t)(sl*8192 + row)*256 + nf*16 + lq] = o[nf][r];
    }
}

// ---------------------------------------------------------------------------
// Combine 4 KV-slices: O = sum_s e^{m_s-M} O_s / sum_s e^{m_s-M} l_s
// ---------------------------------------------------------------------------
__global__ __launch_bounds__(256) void combine_kernel(const float* __restrict__ Opart,
                                                      const float* __restrict__ ml,
                                                      float* __restrict__ out)
{
  const int row = blockIdx.x;
  const int d = threadIdx.x;
  float mm[4], ll[4];
  #pragma unroll
  for (int s=0;s<4;s++){
    mm[s] = ml[(size_t)(s*8192+row)*2 + 0];
    ll[s] = ml[(size_t)(s*8192+row)*2 + 1];
  }
  const float M = fmaxf(fmaxf(mm[0],mm[1]), fmaxf(mm[2],mm[3]));
  float L = 0.f, acc = 0.f;
  #pragma unroll
  for (int s=0;s<4;s++){
    const float e = __expf(mm[s]-M);
    L   += ll[s]*e;
    acc += e * Opart[(size_t)(s*8192+row)*256 + d];
  }
  out[(size_t)row*256 + d] = acc / L;
}

// ---------------------------------------------------------------------------
extern "C" void kernel_launch(void* const* d_in, const int* in_sizes, int n_in,
                              void* d_out, int out_size, void* d_ws, size_t ws_size,
                              hipStream_t stream)
{
  (void)in_sizes; (void)n_in; (void)out_size; (void)ws_size;
  const float* tgt        = (const float*)d_in[0];
  // d_in[1] = reference_points (unused by the reference)
  const float* srcs       = (const float*)d_in[2];
  const float* posemb     = (const float*)d_in[3];
  const float* in_proj_w  = (const float*)d_in[4];
  const float* in_proj_b  = (const float*)d_in[5];
  const float* out_proj_w = (const float*)d_in[6];
  const float* out_proj_b = (const float*)d_in[7];
  const float* lin_q_w    = (const float*)d_in[8];
  const float* lin_q_b    = (const float*)d_in[9];
  const float* lin_k_w    = (const float*)d_in[10];
  const float* lin_k_b    = (const float*)d_in[11];
  const float* lin_v_w    = (const float*)d_in[12];
  const float* lin_v_b    = (const float*)d_in[13];
  const float* lin_o_w    = (const float*)d_in[14];
  const float* lin_o_b    = (const float*)d_in[15];
  const float* norm1_g    = (const float*)d_in[16];
  const float* norm1_b    = (const float*)d_in[17];
  const float* norm2_g    = (const float*)d_in[18];
  const float* norm2_b    = (const float*)d_in[19];
  const float* ffn_w1     = (const float*)d_in[20];
  const float* ffn_b1     = (const float*)d_in[21];
  const float* ffn_w2     = (const float*)d_in[22];
  const float* ffn_b2     = (const float*)d_in[23];
  const float* ffn_norm_g = (const float*)d_in[24];
  const float* ffn_norm_b = (const float*)d_in[25];
  float* out = (float*)d_out;

  char* w = (char*)d_ws;
  const size_t MB = (size_t)1 << 20;
  // Region plan (lifetimes disjoint within each region):
  //  R0 [0,8MB):    qk -> sa -> t2proj
  //  R1 [8,40MB):   saproj -> smat -> Opart -> ffn_out
  //  R2 [40,72MB):  key_b|val_b -> ffn_h
  //  R3 [72,84MB):  qkv -> (query_b @+0 | attn2 @+4MB)
  //  tgt1 @84MB, tgt3 @92MB, ml @100MB
  float*  qk      = (float*)(w + 0);
  float*  sa      = (float*)(w + 0);
  float*  t2proj  = (float*)(w + 0);
  float*  saproj  = (float*)(w + 8*MB);
  float*  smat    = (float*)(w + 8*MB);
  float*  Opart   = (float*)(w + 8*MB);
  float*  ffn_out = (float*)(w + 8*MB);
  __bf16* key_b   = (__bf16*)(w + 40*MB);
  __bf16* val_b   = (__bf16*)(w + 56*MB);
  float*  ffn_h   = (float*)(w + 40*MB);
  __bf16* qkv     = (__bf16*)(w + 72*MB);
  __bf16* query_b = (__bf16*)(w + 72*MB);
  float*  attn2   = (float*)(w + 76*MB);
  float*  tgt1    = (float*)(w + 84*MB);
  float*  tgt3    = (float*)(w + 92*MB);
  float*  ml      = (float*)(w + 100*MB);

  // ---- Stage A: self-attention ----
  add_vec4<<<2048,256,0,stream>>>(tgt, posemb, qk, (8*1024*256)/4);
  // q,k projections from qk (wq,wk are rows 0..511 of in_proj_w)
  gemm_bt<false,true><<<dim3(64,8),256,0,stream>>>(qk, in_proj_w, in_proj_b,
      qkv, 8192,512,256, 768,0);
  // v projection from tgt
  gemm_bt<false,true><<<dim3(64,4),256,0,stream>>>(tgt, in_proj_w + 512*256,
      in_proj_b + 512, qkv, 8192,256,256, 768,512);
  flash_self<<<dim3(16,64),256,0,stream>>>(qkv, sa);
  gemm_bt<false,false><<<dim3(64,4),256,0,stream>>>(sa, out_proj_w, out_proj_b,
      saproj, 8192,256,256, 256,0);
  ln_kernel<<<2048,256,0,stream>>>(tgt, saproj, norm2_g, norm2_b, tgt1);

  // ---- Stage B: cross-attention ----
  transpose_srcs<<<dim3(128,8,8),256,0,stream>>>(srcs, smat);
  gemm_bt<false,true><<<dim3(64,4),256,0,stream>>>(tgt1, lin_q_w, lin_q_b,
      query_b, 8192,256,256, 256,0);
  gemm_bt<false,true><<<dim3(256,4),256,0,stream>>>(smat, lin_k_w, lin_k_b,
      key_b, 32768,256,256, 256,0);
  gemm_bt<false,true><<<dim3(256,4),256,0,stream>>>(smat, lin_v_w, lin_v_b,
      val_b, 32768,256,256, 256,0);
  flash_cross<<<dim3(16,8,4),256,0,stream>>>(query_b, key_b, val_b, Opart, ml);
  combine_kernel<<<8192,256,0,stream>>>(Opart, ml, attn2);
  gemm_bt<false,false><<<dim3(64,4),256,0,stream>>>(attn2, lin_o_w, lin_o_b,
      t2proj, 8192,256,256, 256,0);
  ln_kernel<<<2048,256,0,stream>>>(tgt1, t2proj, norm1_g, norm1_b, tgt3);

  // ---- Stage C: FFN ----
  gemm_bt<true,false><<<dim3(64,16),256,0,stream>>>(tgt3, ffn_w1, ffn_b1,
      ffn_h, 8192,1024,256, 1024,0);
  gemm_bt<false,false><<<dim3(64,4),256,0,stream>>>(ffn_h, ffn_w2, ffn_b2,
      ffn_out, 8192,256,1024, 256,0);
  ln_kernel<<<2048,256,0,stream>>>(tgt3, ffn_out, ffn_norm_g, ffn_norm_b, out);
}

// Round 2
// 322.806 us; speedup vs baseline: 1.0924x; 1.0924x over previous
//
#include <hip/hip_runtime.h>
#include <hip/hip_bf16.h>
#include <math.h>

typedef __attribute__((ext_vector_type(8))) __bf16 bf16x8;
typedef __attribute__((ext_vector_type(4))) __bf16 bf16x4;
typedef __attribute__((ext_vector_type(2))) __bf16 bf16x2;
typedef __attribute__((ext_vector_type(4))) float  f32x4;

#define MFMA16(a,b,c) __builtin_amdgcn_mfma_f32_16x16x32_bf16((a),(b),(c),0,0,0)

__device__ __forceinline__ float wave16_max(float v){
  v = fmaxf(v, __shfl_xor(v,1));
  v = fmaxf(v, __shfl_xor(v,2));
  v = fmaxf(v, __shfl_xor(v,4));
  v = fmaxf(v, __shfl_xor(v,8));
  return v;
}
__device__ __forceinline__ float wave16_sum(float v){
  v += __shfl_xor(v,1);
  v += __shfl_xor(v,2);
  v += __shfl_xor(v,4);
  v += __shfl_xor(v,8);
  return v;
}
__device__ __forceinline__ unsigned pack2bf(float a, float b){
  bf16x2 t; t[0] = (__bf16)a; t[1] = (__bf16)b;
  return __builtin_bit_cast(unsigned, t);
}

// ---------------------------------------------------------------------------
// Generic GEMM: C[M,N] = A[M,K] @ W[N,K]^T + bias, fp32 inputs, bf16 MFMA.
// BM=128, BN=64, BK=32, 256 threads (4 waves, 2x2), each wave 64x32.
// ---------------------------------------------------------------------------
template<bool RELU, bool BF16OUT>
__global__ __launch_bounds__(256) void gemm_bt(
    const float* __restrict__ A, const float* __restrict__ W,
    const float* __restrict__ bias, void* __restrict__ Cv,
    int M, int N, int K, int ldc, int coff)
{
  __shared__ __align__(16) __bf16 As[128][40];
  __shared__ __align__(16) __bf16 Bs[64][40];

  const int tid  = threadIdx.x;
  const int wid  = tid >> 6;
  const int lane = tid & 63;
  const int wr   = wid >> 1;
  const int wc   = wid & 1;
  const int lq   = lane & 15;
  const int lk8  = (lane >> 4) << 3;
  const int rb   = (lane >> 4) << 2;

  const int m0 = blockIdx.x * 128;
  const int n0 = blockIdx.y * 64;

  const int scg = (tid & 7) << 2;
  const int sr  = tid >> 3;

  f32x4 acc[4][2];
  #pragma unroll
  for (int i=0;i<4;i++)
    #pragma unroll
    for (int j=0;j<2;j++) acc[i][j] = f32x4{0.f,0.f,0.f,0.f};

  for (int k0=0; k0<K; k0+=32){
    __syncthreads();
    #pragma unroll
    for (int i=0;i<4;i++){
      const int row = sr + i*32;
      const float4 a4 = *(const float4*)&A[(size_t)(m0+row)*K + k0 + scg];
      bf16x4 h; h[0]=(__bf16)a4.x; h[1]=(__bf16)a4.y; h[2]=(__bf16)a4.z; h[3]=(__bf16)a4.w;
      *(bf16x4*)&As[row][scg] = h;
    }
    #pragma unroll
    for (int i=0;i<2;i++){
      const int row = sr + i*32;
      const float4 a4 = *(const float4*)&W[(size_t)(n0+row)*K + k0 + scg];
      bf16x4 h; h[0]=(__bf16)a4.x; h[1]=(__bf16)a4.y; h[2]=(__bf16)a4.z; h[3]=(__bf16)a4.w;
      *(bf16x4*)&Bs[row][scg] = h;
    }
    __syncthreads();
    bf16x8 af[4], bfr[2];
    #pragma unroll
    for (int i=0;i<4;i++) af[i]  = *(const bf16x8*)&As[wr*64 + i*16 + lq][lk8];
    #pragma unroll
    for (int j=0;j<2;j++) bfr[j] = *(const bf16x8*)&Bs[wc*32 + j*16 + lq][lk8];
    #pragma unroll
    for (int i=0;i<4;i++)
      #pragma unroll
      for (int j=0;j<2;j++)
        acc[i][j] = MFMA16(af[i], bfr[j], acc[i][j]);
  }

  #pragma unroll
  for (int i=0;i<4;i++)
    #pragma unroll
    for (int j=0;j<2;j++){
      const int coln = n0 + wc*32 + j*16 + lq;
      const float bv = bias ? bias[coln] : 0.f;
      #pragma unroll
      for (int r=0;r<4;r++){
        const int rowm = m0 + wr*64 + i*16 + rb + r;
        float vv = acc[i][j][r] + bv;
        if (RELU) vv = fmaxf(vv, 0.f);
        const size_t idx = (size_t)rowm*ldc + coff + coln;
        if (BF16OUT) ((__bf16*)Cv)[idx] = (__bf16)vv;
        else         ((float*)Cv)[idx]  = vv;
      }
    }
}

// ---------------------------------------------------------------------------
// GEMM with A staged (transposed) directly from srcs[8][256][4096]:
// C[m = b*4096+p][n] = sum_c srcs[b][c][p] * W[n][c] + bias[n]
// TRANSOUT=false: C row-major [32768][256] bf16 (key_b)
// TRANSOUT=true:  C = [8][256][4096] bf16 (val_t, d-major)
// ---------------------------------------------------------------------------
template<bool TRANSOUT>
__global__ __launch_bounds__(256) void gemm_srcs(
    const float* __restrict__ S, const float* __restrict__ W,
    const float* __restrict__ bias, __bf16* __restrict__ C)
{
  __shared__ __align__(16) __bf16 As[128][40];
  __shared__ __align__(16) __bf16 Bs[64][40];

  const int tid  = threadIdx.x;
  const int wid  = tid >> 6;
  const int lane = tid & 63;
  const int wr   = wid >> 1;
  const int wc   = wid & 1;
  const int lq   = lane & 15;
  const int lk8  = (lane >> 4) << 3;
  const int rb   = (lane >> 4) << 2;

  const int m0 = blockIdx.x * 128;
  const int n0 = blockIdx.y * 64;
  const int bb = m0 >> 12;
  const int p0 = m0 & 4095;

  const int cA = tid & 31;   // k (channel) column 0..31
  const int qA = tid >> 5;   // 0..7: p-quad within 32-p group
  const int scg = (tid & 7) << 2;
  const int sr  = tid >> 3;

  f32x4 acc[4][2];
  #pragma unroll
  for (int i=0;i<4;i++)
    #pragma unroll
    for (int j=0;j<2;j++) acc[i][j] = f32x4{0.f,0.f,0.f,0.f};

  for (int k0=0; k0<256; k0+=32){
    __syncthreads();
    // A-tile: transpose-stage from srcs (contiguous along p)
    const float* sbase = &S[((size_t)bb*256 + k0 + cA)*4096 + p0];
    #pragma unroll
    for (int ps=0; ps<4; ps++){
      const int p = ps*32 + qA*4;
      const float4 f4 = *(const float4*)(sbase + p);
      As[p+0][cA] = (__bf16)f4.x;
      As[p+1][cA] = (__bf16)f4.y;
      As[p+2][cA] = (__bf16)f4.z;
      As[p+3][cA] = (__bf16)f4.w;
    }
    #pragma unroll
    for (int i=0;i<2;i++){
      const int row = sr + i*32;
      const float4 a4 = *(const float4*)&W[(size_t)(n0+row)*256 + k0 + scg];
      bf16x4 h; h[0]=(__bf16)a4.x; h[1]=(__bf16)a4.y; h[2]=(__bf16)a4.z; h[3]=(__bf16)a4.w;
      *(bf16x4*)&Bs[row][scg] = h;
    }
    __syncthreads();
    bf16x8 af[4], bfr[2];
    #pragma unroll
    for (int i=0;i<4;i++) af[i]  = *(const bf16x8*)&As[wr*64 + i*16 + lq][lk8];
    #pragma unroll
    for (int j=0;j<2;j++) bfr[j] = *(const bf16x8*)&Bs[wc*32 + j*16 + lq][lk8];
    #pragma unroll
    for (int i=0;i<4;i++)
      #pragma unroll
      for (int j=0;j<2;j++)
        acc[i][j] = MFMA16(af[i], bfr[j], acc[i][j]);
  }

  #pragma unroll
  for (int i=0;i<4;i++)
    #pragma unroll
    for (int j=0;j<2;j++){
      const int coln = n0 + wc*32 + j*16 + lq;
      const float bv = bias ? bias[coln] : 0.f;
      if (TRANSOUT){
        bf16x4 hv;
        #pragma unroll
        for (int r=0;r<4;r++) hv[r] = (__bf16)(acc[i][j][r] + bv);
        *(bf16x4*)&C[((size_t)bb*256 + coln)*4096 + p0 + wr*64 + i*16 + rb] = hv;
      } else {
        #pragma unroll
        for (int r=0;r<4;r++){
          const int rowm = m0 + wr*64 + i*16 + rb + r;
          C[(size_t)rowm*256 + coln] = (__bf16)(acc[i][j][r] + bv);
        }
      }
    }
}

// ---------------------------------------------------------------------------
__global__ __launch_bounds__(256) void add_vec4(const float* __restrict__ a,
                                                const float* __restrict__ b,
                                                float* __restrict__ o, int n4)
{
  const int i = blockIdx.x*blockDim.x + threadIdx.x;
  if (i < n4){
    const float4 x = ((const float4*)a)[i];
    const float4 y = ((const float4*)b)[i];
    float4 z; z.x=x.x+y.x; z.y=x.y+y.y; z.z=x.z+y.z; z.w=x.w+y.w;
    ((float4*)o)[i] = z;
  }
}

// ---------------------------------------------------------------------------
__global__ __launch_bounds__(256) void ln_kernel(const float* __restrict__ res,
                                                 const float* __restrict__ x,
                                                 const float* __restrict__ g,
                                                 const float* __restrict__ beta,
                                                 float* __restrict__ out)
{
  const int row  = blockIdx.x*4 + (threadIdx.x >> 6);
  const int lane = threadIdx.x & 63;
  const int c = lane*4;
  const float4 rv = *(const float4*)&res[(size_t)row*256 + c];
  const float4 xv = *(const float4*)&x[(size_t)row*256 + c];
  float v0=rv.x+xv.x, v1=rv.y+xv.y, v2=rv.z+xv.z, v3=rv.w+xv.w;
  float s = v0+v1+v2+v3;
  #pragma unroll
  for (int off=1; off<64; off<<=1) s += __shfl_xor(s, off);
  const float mean = s * (1.f/256.f);
  const float d0=v0-mean, d1=v1-mean, d2=v2-mean, d3=v3-mean;
  float q = d0*d0 + d1*d1 + d2*d2 + d3*d3;
  #pragma unroll
  for (int off=1; off<64; off<<=1) q += __shfl_xor(q, off);
  const float rstd = rsqrtf(q*(1.f/256.f) + 1e-5f);
  const float4 gv = *(const float4*)&g[c];
  const float4 bv = *(const float4*)&beta[c];
  float4 ov;
  ov.x = d0*rstd*gv.x + bv.x;
  ov.y = d1*rstd*gv.y + bv.y;
  ov.z = d2*rstd*gv.z + bv.z;
  ov.w = d3*rstd*gv.w + bv.w;
  *(float4*)&out[(size_t)row*256 + c] = ov;
}

// ---------------------------------------------------------------------------
// Flash self-attention. qkv bf16 [8192][768] (q:0-255, k:256-511, v:512-767).
// ---------------------------------------------------------------------------
__global__ __launch_bounds__(256) void flash_self(const __bf16* __restrict__ qkv,
                                                  float* __restrict__ sa)
{
  const int qt = blockIdx.x;
  const int b  = blockIdx.y >> 3;
  const int h  = blockIdx.y & 7;
  const int tid  = threadIdx.x;
  const int wid  = tid >> 6;
  const int lane = tid & 63;
  const int lq   = lane & 15;
  const int lk8  = (lane >> 4) << 3;
  const int rb   = (lane >> 4) << 2;

  __shared__ __align__(16) __bf16 Vt[32][40];
  __shared__ __align__(16) __bf16 Pl[4][16][40];

  const int qrow = b*1024 + qt*64 + wid*16 + lq;
  const bf16x8 qf = *(const bf16x8*)&qkv[(size_t)qrow*768 + h*32 + lk8];

  float m[4], l[4];
  f32x4 o[2];
  #pragma unroll
  for (int r=0;r<4;r++){ m[r] = -1e30f; l[r] = 0.f; }
  o[0] = f32x4{0.f,0.f,0.f,0.f};
  o[1] = f32x4{0.f,0.f,0.f,0.f};

  const int vk = tid & 31;
  const int vd = (tid >> 5) << 2;
  const float scale = 0.17677669529663687f;

  for (int kc=0; kc<32; ++kc){
    const int key0 = kc*32;
    __syncthreads();
    {
      const bf16x4 vv = *(const bf16x4*)&qkv[(size_t)(b*1024 + key0 + vk)*768 + 512 + h*32 + vd];
      #pragma unroll
      for (int j=0;j<4;j++) Vt[vd+j][vk] = vv[j];
    }
    const __bf16* kbase = &qkv[(size_t)(b*1024 + key0)*768 + 256 + h*32 + lk8];
    const bf16x8 kf0 = *(const bf16x8*)(kbase + (size_t)lq*768);
    const bf16x8 kf1 = *(const bf16x8*)(kbase + (size_t)(16+lq)*768);
    const f32x4 z = f32x4{0.f,0.f,0.f,0.f};
    const f32x4 s0 = MFMA16(qf, kf0, z);
    const f32x4 s1 = MFMA16(qf, kf1, z);
    #pragma unroll
    for (int r=0;r<4;r++){
      const float a0 = s0[r]*scale, a1 = s1[r]*scale;
      const float mx = wave16_max(fmaxf(a0,a1));
      const float mn = fmaxf(m[r], mx);
      const float alpha = __expf(m[r]-mn);
      const float p0 = __expf(a0-mn);
      const float p1 = __expf(a1-mn);
      const float rs = wave16_sum(p0+p1);
      l[r] = l[r]*alpha + rs;
      o[0][r] *= alpha;
      o[1][r] *= alpha;
      m[r] = mn;
      Pl[wid][rb+r][lq]      = (__bf16)p0;
      Pl[wid][rb+r][16+lq]   = (__bf16)p1;
    }
    __syncthreads();
    const bf16x8 pf  = *(const bf16x8*)&Pl[wid][lq][lk8];
    const bf16x8 vf0 = *(const bf16x8*)&Vt[lq][lk8];
    const bf16x8 vf1 = *(const bf16x8*)&Vt[16+lq][lk8];
    o[0] = MFMA16(pf, vf0, o[0]);
    o[1] = MFMA16(pf, vf1, o[1]);
  }
  #pragma unroll
  for (int nf=0;nf<2;nf++)
    #pragma unroll
    for (int r=0;r<4;r++){
      const int row = b*1024 + qt*64 + wid*16 + rb + r;
      sa[(size_t)row*256 + h*32 + nf*16 + lq] = o[nf][r] / l[r];
    }
}

// ---------------------------------------------------------------------------
// Flash cross-attention, swapped-operand form, P kept in registers.
// q bf16 [8192][256]; k bf16 [8][4096][256]; vt bf16 [8][256][4096].
// Block = (qtile 64, b, slice of 1024 keys); 4 waves; KVBLK=64.
// Each lane owns ONE q-row (q = wid*16 + lane&15); m,l scalars.
// LDS: Ks[64][256] + Vt[256][64], both XOR-swizzled in 16B chunks (64 KiB).
// ---------------------------------------------------------------------------
__global__ __launch_bounds__(256, 2) void flash_cross(
    const __bf16* __restrict__ qg, const __bf16* __restrict__ kg,
    const __bf16* __restrict__ vtg, float* __restrict__ Opart,
    float* __restrict__ ml)
{
  extern __shared__ __bf16 smem[];
  __bf16* Ks = smem;            // [64][256]
  __bf16* Vt = smem + 64*256;   // [256][64]

  const int qt = blockIdx.x;
  const int b  = blockIdx.y;
  const int sl = blockIdx.z;
  const int tid  = threadIdx.x;
  const int wid  = tid >> 6;
  const int lane = tid & 63;
  const int lq   = lane & 15;
  const int hi   = lane >> 4;
  const int lk8  = hi << 3;
  const int rb   = hi << 2;
  const int swz  = lq & 7;

  const int qrow = b*1024 + qt*64 + wid*16 + lq;
  bf16x8 qf[8];
  #pragma unroll
  for (int ks=0; ks<8; ks++)
    qf[ks] = *(const bf16x8*)&qg[(size_t)qrow*256 + ks*32 + lk8];

  float m = -1e30f, l = 0.f;
  f32x4 o[16];
  #pragma unroll
  for (int nf=0; nf<16; nf++) o[nf] = f32x4{0.f,0.f,0.f,0.f};

  const int srow = tid >> 2;   // 0..63
  const int sc4  = tid & 3;

  for (int it=0; it<16; ++it){
    const int key0 = sl*1024 + it*64;
    __syncthreads();
    { // stage K tile [64 keys][256 ch], swizzled
      const __bf16* kb = &kg[(size_t)(b*4096 + key0 + srow)*256];
      #pragma unroll
      for (int j=0;j<8;j++){
        const int ch = sc4 + j*4;
        const bf16x8 vv = *(const bf16x8*)(kb + ch*8);
        *(bf16x8*)&Ks[srow*256 + ((ch ^ (srow&7))<<3)] = vv;
      }
    }
    { // stage V^T tile [256 d][64 keys], swizzled (vtg rows contiguous in key)
      #pragma unroll
      for (int ps=0; ps<4; ps++){
        const int d = srow + ps*64;
        const __bf16* vb = &vtg[(size_t)(b*256 + d)*4096 + key0];
        #pragma unroll
        for (int s2=0;s2<2;s2++){
          const int ch = sc4 + s2*4;
          const bf16x8 vv = *(const bf16x8*)(vb + ch*8);
          *(bf16x8*)&Vt[d*64 + ((ch ^ (d&7))<<3)] = vv;
        }
      }
    }
    __syncthreads();
    // S^T = K · Q^T : s4[kt][r] = S[key = kt*16 + rb + r][q-col = lq]
    f32x4 s4[4];
    #pragma unroll
    for (int kt=0;kt<4;kt++) s4[kt] = f32x4{0.f,0.f,0.f,0.f};
    #pragma unroll
    for (int ks=0; ks<8; ks++){
      #pragma unroll
      for (int kt=0; kt<4; kt++){
        const bf16x8 kf = *(const bf16x8*)&Ks[(kt*16+lq)*256 + (((ks*4+hi) ^ swz)<<3)];
        s4[kt] = MFMA16(kf, qf[ks], s4[kt]);
      }
    }
    // online softmax for this lane's q-row (16 vals per thread + 2 shfl)
    float pm = s4[0][0];
    #pragma unroll
    for (int kt=0;kt<4;kt++)
      #pragma unroll
      for (int r=0;r<4;r++) pm = fmaxf(pm, s4[kt][r]);
    pm = fmaxf(pm, __shfl_xor(pm, 16));
    pm = fmaxf(pm, __shfl_xor(pm, 32));
    if (!__all(pm <= m + 8.f)){   // defer-max (T13)
      const float mn = fmaxf(m, pm);
      const float alpha = __expf(m - mn);
      #pragma unroll
      for (int nf=0;nf<16;nf++){
        o[nf][0]*=alpha; o[nf][1]*=alpha; o[nf][2]*=alpha; o[nf][3]*=alpha;
      }
      l *= alpha;
      m = mn;
    }
    float p[4][4];
    float rs = 0.f;
    #pragma unroll
    for (int kt=0;kt<4;kt++)
      #pragma unroll
      for (int r=0;r<4;r++){ p[kt][r] = __expf(s4[kt][r] - m); rs += p[kt][r]; }
    rs += __shfl_xor(rs, 16);
    rs += __shfl_xor(rs, 32);
    l += rs;
    // pack P (q = lq, key = kt*16 + 4*hi + r) and redistribute to B-frag layout:
    // pf[ks2] element j at lane (hi,lq) = P[q=lq][key = ks2*32 + hi*8 + j]
    unsigned pk0[4], pk1[4];
    #pragma unroll
    for (int kt=0;kt<4;kt++){
      pk0[kt] = pack2bf(p[kt][0], p[kt][1]);
      pk1[kt] = pack2bf(p[kt][2], p[kt][3]);
    }
    const int srcA = ((hi&1)<<5) + lq;
    const int srcB = srcA + 16;
    const bool ksel = hi >= 2;
    bf16x8 pf[2];
    #pragma unroll
    for (int ks2=0; ks2<2; ks2++){
      const unsigned a0 = (unsigned)__shfl((int)pk0[2*ks2],   srcA);
      const unsigned a1 = (unsigned)__shfl((int)pk0[2*ks2+1], srcA);
      const unsigned b0 = (unsigned)__shfl((int)pk1[2*ks2],   srcA);
      const unsigned b1 = (unsigned)__shfl((int)pk1[2*ks2+1], srcA);
      const unsigned c0 = (unsigned)__shfl((int)pk0[2*ks2],   srcB);
      const unsigned c1 = (unsigned)__shfl((int)pk0[2*ks2+1], srcB);
      const unsigned d0 = (unsigned)__shfl((int)pk1[2*ks2],   srcB);
      const unsigned d1 = (unsigned)__shfl((int)pk1[2*ks2+1], srcB);
      union { unsigned u[4]; bf16x8 v; } uu;
      uu.u[0] = ksel ? a1 : a0;
      uu.u[1] = ksel ? b1 : b0;
      uu.u[2] = ksel ? c1 : c0;
      uu.u[3] = ksel ? d1 : d0;
      pf[ks2] = uu.v;
    }
    // O^T += V^T · P^T : o[nf][r] = O[q=lq][d = nf*16 + rb + r]
    #pragma unroll
    for (int nf=0; nf<16; nf++){
      #pragma unroll
      for (int ks2=0; ks2<2; ks2++){
        const bf16x8 af = *(const bf16x8*)&Vt[(nf*16+lq)*64 + (((ks2*4+hi) ^ swz)<<3)];
        o[nf] = MFMA16(af, pf[ks2], o[nf]);
      }
    }
  }
  const int row = b*1024 + qt*64 + wid*16 + lq;
  if (hi == 0){
    ml[(size_t)(sl*8192 + row)*2 + 0] = m;
    ml[(size_t)(sl*8192 + row)*2 + 1] = l;
  }
  #pragma unroll
  for (int nf=0; nf<16; nf++)
    *(f32x4*)&Opart[(size_t)(sl*8192 + row)*256 + nf*16 + rb] = o[nf];
}

// ---------------------------------------------------------------------------
__global__ __launch_bounds__(256) void combine_kernel(const float* __restrict__ Opart,
                                                      const float* __restrict__ ml,
                                                      float* __restrict__ out)
{
  const int row = blockIdx.x;
  const int d = threadIdx.x;
  float mm[4], ll[4];
  #pragma unroll
  for (int s=0;s<4;s++){
    mm[s] = ml[(size_t)(s*8192+row)*2 + 0];
    ll[s] = ml[(size_t)(s*8192+row)*2 + 1];
  }
  const float M = fmaxf(fmaxf(mm[0],mm[1]), fmaxf(mm[2],mm[3]));
  float L = 0.f, acc = 0.f;
  #pragma unroll
  for (int s=0;s<4;s++){
    const float e = __expf(mm[s]-M);
    L   += ll[s]*e;
    acc += e * Opart[(size_t)(s*8192+row)*256 + d];
  }
  out[(size_t)row*256 + d] = acc / L;
}

// ---------------------------------------------------------------------------
extern "C" void kernel_launch(void* const* d_in, const int* in_sizes, int n_in,
                              void* d_out, int out_size, void* d_ws, size_t ws_size,
                              hipStream_t stream)
{
  (void)in_sizes; (void)n_in; (void)out_size; (void)ws_size;
  const float* tgt        = (const float*)d_in[0];
  const float* srcs       = (const float*)d_in[2];
  const float* posemb     = (const float*)d_in[3];
  const float* in_proj_w  = (const float*)d_in[4];
  const float* in_proj_b  = (const float*)d_in[5];
  const float* out_proj_w = (const float*)d_in[6];
  const float* out_proj_b = (const float*)d_in[7];
  const float* lin_q_w    = (const float*)d_in[8];
  const float* lin_q_b    = (const float*)d_in[9];
  const float* lin_k_w    = (const float*)d_in[10];
  const float* lin_k_b    = (const float*)d_in[11];
  const float* lin_v_w    = (const float*)d_in[12];
  const float* lin_v_b    = (const float*)d_in[13];
  const float* lin_o_w    = (const float*)d_in[14];
  const float* lin_o_b    = (const float*)d_in[15];
  const float* norm1_g    = (const float*)d_in[16];
  const float* norm1_b    = (const float*)d_in[17];
  const float* norm2_g    = (const float*)d_in[18];
  const float* norm2_b    = (const float*)d_in[19];
  const float* ffn_w1     = (const float*)d_in[20];
  const float* ffn_b1     = (const float*)d_in[21];
  const float* ffn_w2     = (const float*)d_in[22];
  const float* ffn_b2     = (const float*)d_in[23];
  const float* ffn_norm_g = (const float*)d_in[24];
  const float* ffn_norm_b = (const float*)d_in[25];
  float* out = (float*)d_out;

  char* w = (char*)d_ws;
  const size_t MB = (size_t)1 << 20;
  // Region plan (lifetimes verified in sequence below), peak 82.25 MB:
  float*  tgt1    = (float*)(w + 0);        // stage-A out, live to ln(norm1)
  float*  qk      = (float*)(w + 8*MB);     // dead after qkv gemm
  float*  sa      = (float*)(w + 8*MB);     // dead after out_proj
  __bf16* query_b = (__bf16*)(w + 8*MB);    // dead after flash_cross
  float*  attn2   = (float*)(w + 8*MB);     // written by combine
  __bf16* qkv     = (__bf16*)(w + 16*MB);   // 12.6MB, dead after flash_self
  float*  saproj  = (float*)(w + 16*MB);    // dead after ln(norm2)
  __bf16* key_b   = (__bf16*)(w + 16*MB);   // 16MB, dead after flash_cross
  float*  t2proj  = (float*)(w + 16*MB);    // written by lin_o
  float*  tgt3    = (float*)(w + 24*MB);    // live to end
  __bf16* val_t   = (__bf16*)(w + 32*MB);   // 16MB, dead after flash_cross
  float*  ffn_h   = (float*)(w + 32*MB);    // 32MB, FFN stage
  float*  Opart   = (float*)(w + 48*MB);    // 33.5MB, dead after combine
  float*  ffn_out = (float*)(w + 64*MB);    // FFN stage (Opart dead)
  float*  ml      = (float*)(w + 82*MB);

  // ---- Stage A: self-attention ----
  add_vec4<<<2048,256,0,stream>>>(tgt, posemb, qk, (8*1024*256)/4);
  gemm_bt<false,true><<<dim3(64,8),256,0,stream>>>(qk, in_proj_w, in_proj_b,
      qkv, 8192,512,256, 768,0);
  gemm_bt<false,true><<<dim3(64,4),256,0,stream>>>(tgt, in_proj_w + 512*256,
      in_proj_b + 512, qkv, 8192,256,256, 768,512);
  flash_self<<<dim3(16,64),256,0,stream>>>(qkv, sa);
  gemm_bt<false,false><<<dim3(64,4),256,0,stream>>>(sa, out_proj_w, out_proj_b,
      saproj, 8192,256,256, 256,0);
  ln_kernel<<<2048,256,0,stream>>>(tgt, saproj, norm2_g, norm2_b, tgt1);

  // ---- Stage B: cross-attention (transpose fused into K/V gemms) ----
  gemm_bt<false,true><<<dim3(64,4),256,0,stream>>>(tgt1, lin_q_w, lin_q_b,
      query_b, 8192,256,256, 256,0);
  gemm_srcs<false><<<dim3(256,4),256,0,stream>>>(srcs, lin_k_w, lin_k_b, key_b);
  gemm_srcs<true ><<<dim3(256,4),256,0,stream>>>(srcs, lin_v_w, lin_v_b, val_t);
  flash_cross<<<dim3(16,8,4),256,65536,stream>>>(query_b, key_b, val_t, Opart, ml);
  combine_kernel<<<8192,256,0,stream>>>(Opart, ml, attn2);
  gemm_bt<false,false><<<dim3(64,4),256,0,stream>>>(attn2, lin_o_w, lin_o_b,
      t2proj, 8192,256,256, 256,0);
  ln_kernel<<<2048,256,0,stream>>>(tgt1, t2proj, norm1_g, norm1_b, tgt3);

  // ---- Stage C: FFN ----
  gemm_bt<true,false><<<dim3(64,16),256,0,stream>>>(tgt3, ffn_w1, ffn_b1,
      ffn_h, 8192,1024,256, 1024,0);
  gemm_bt<false,false><<<dim3(64,4),256,0,stream>>>(ffn_h, ffn_w2, ffn_b2,
      ffn_out, 8192,256,1024, 256,0);
  ln_kernel<<<2048,256,0,stream>>>(tgt3, ffn_out, ffn_norm_g, ffn_norm_b, out);
}

// Round 4
// 297.141 us; speedup vs baseline: 1.1868x; 1.0864x over previous
//
#include <hip/hip_runtime.h>
#include <hip/hip_bf16.h>
#include <math.h>

typedef __attribute__((ext_vector_type(8))) __bf16 bf16x8;
typedef __attribute__((ext_vector_type(4))) __bf16 bf16x4;
typedef __attribute__((ext_vector_type(2))) __bf16 bf16x2;
typedef __attribute__((ext_vector_type(4))) float  f32x4;

#define MFMA16(a,b,c) __builtin_amdgcn_mfma_f32_16x16x32_bf16((a),(b),(c),0,0,0)

__device__ __forceinline__ unsigned pack2bf(float a, float b){
  bf16x2 t; t[0] = (__bf16)a; t[1] = (__bf16)b;
  return __builtin_bit_cast(unsigned, t);
}

// ---------------------------------------------------------------------------
// Generic GEMM: C[M,N] = (A[M,K] @ W[N,K]^T + bias) * oscale, bf16 MFMA.
// BM in {64,128}, BN=64, BK=32, 256 threads (4 waves, 2x2).
// OUTMODE: 0 = f32 row-major (ldc,coff), 1 = bf16 row-major (ldc,coff),
//          2 = bf16 transposed C_t[(row>>10)*256 + n][row&1023]  (v_t layout)
// ---------------------------------------------------------------------------
template<int BM, bool RELU, int OUTMODE>
__global__ __launch_bounds__(256) void gemm_bt(
    const float* __restrict__ A, const float* __restrict__ W,
    const float* __restrict__ bias, void* __restrict__ Cv,
    int M, int N, int K, int ldc, int coff, float oscale)
{
  constexpr int MT = BM/32;   // m-tiles per wave
  __shared__ __align__(16) __bf16 As[BM][40];
  __shared__ __align__(16) __bf16 Bs[64][40];

  const int tid  = threadIdx.x;
  const int wid  = tid >> 6;
  const int lane = tid & 63;
  const int wr   = wid >> 1;
  const int wc   = wid & 1;
  const int lq   = lane & 15;
  const int lk8  = (lane >> 4) << 3;
  const int rb   = (lane >> 4) << 2;

  const int m0 = blockIdx.x * BM;
  const int n0 = blockIdx.y * 64;

  const int scg = (tid & 7) << 2;
  const int sr  = tid >> 3;

  f32x4 acc[MT][2];
  #pragma unroll
  for (int i=0;i<MT;i++)
    #pragma unroll
    for (int j=0;j<2;j++) acc[i][j] = f32x4{0.f,0.f,0.f,0.f};

  for (int k0=0; k0<K; k0+=32){
    __syncthreads();
    #pragma unroll
    for (int i=0;i<MT;i++){
      const int row = sr + i*32;
      const float4 a4 = *(const float4*)&A[(size_t)(m0+row)*K + k0 + scg];
      bf16x4 h; h[0]=(__bf16)a4.x; h[1]=(__bf16)a4.y; h[2]=(__bf16)a4.z; h[3]=(__bf16)a4.w;
      *(bf16x4*)&As[row][scg] = h;
    }
    #pragma unroll
    for (int i=0;i<2;i++){
      const int row = sr + i*32;
      const float4 a4 = *(const float4*)&W[(size_t)(n0+row)*K + k0 + scg];
      bf16x4 h; h[0]=(__bf16)a4.x; h[1]=(__bf16)a4.y; h[2]=(__bf16)a4.z; h[3]=(__bf16)a4.w;
      *(bf16x4*)&Bs[row][scg] = h;
    }
    __syncthreads();
    bf16x8 af[MT], bfr[2];
    #pragma unroll
    for (int i=0;i<MT;i++) af[i]  = *(const bf16x8*)&As[wr*(BM/2) + i*16 + lq][lk8];
    #pragma unroll
    for (int j=0;j<2;j++)  bfr[j] = *(const bf16x8*)&Bs[wc*32 + j*16 + lq][lk8];
    #pragma unroll
    for (int i=0;i<MT;i++)
      #pragma unroll
      for (int j=0;j<2;j++)
        acc[i][j] = MFMA16(af[i], bfr[j], acc[i][j]);
  }

  #pragma unroll
  for (int i=0;i<MT;i++)
    #pragma unroll
    for (int j=0;j<2;j++){
      const int coln = n0 + wc*32 + j*16 + lq;
      const float bv = bias ? bias[coln] : 0.f;
      if (OUTMODE == 2){
        const int rowm0 = m0 + wr*(BM/2) + i*16 + rb;
        bf16x4 hv;
        #pragma unroll
        for (int r=0;r<4;r++){
          float vv = (acc[i][j][r] + bv) * oscale;
          if (RELU) vv = fmaxf(vv, 0.f);
          hv[r] = (__bf16)vv;
        }
        *(bf16x4*)&((__bf16*)Cv)[((size_t)((rowm0>>10)*256) + coln)*1024 + (rowm0&1023)] = hv;
      } else {
        #pragma unroll
        for (int r=0;r<4;r++){
          const int rowm = m0 + wr*(BM/2) + i*16 + rb + r;
          float vv = (acc[i][j][r] + bv) * oscale;
          if (RELU) vv = fmaxf(vv, 0.f);
          const size_t idx = (size_t)rowm*ldc + coff + coln;
          if (OUTMODE == 1) ((__bf16*)Cv)[idx] = (__bf16)vv;
          else              ((float*)Cv)[idx]  = vv;
        }
      }
    }
}

// ---------------------------------------------------------------------------
// GEMM with A staged (transposed) directly from srcs[8][256][4096]:
// C[m = b*4096+p][n] = sum_c srcs[b][c][p] * W[n][c] + bias[n]
// TRANSOUT=false: C row-major [32768][256] bf16 (key_b)
// TRANSOUT=true:  C = [8][256][4096] bf16 (val_t, d-major)
// ---------------------------------------------------------------------------
template<bool TRANSOUT>
__global__ __launch_bounds__(256) void gemm_srcs(
    const float* __restrict__ S, const float* __restrict__ W,
    const float* __restrict__ bias, __bf16* __restrict__ C)
{
  __shared__ __align__(16) __bf16 As[128][40];
  __shared__ __align__(16) __bf16 Bs[64][40];

  const int tid  = threadIdx.x;
  const int wid  = tid >> 6;
  const int lane = tid & 63;
  const int wr   = wid >> 1;
  const int wc   = wid & 1;
  const int lq   = lane & 15;
  const int lk8  = (lane >> 4) << 3;
  const int rb   = (lane >> 4) << 2;

  const int m0 = blockIdx.x * 128;
  const int n0 = blockIdx.y * 64;
  const int bb = m0 >> 12;
  const int p0 = m0 & 4095;

  const int cA = tid & 31;
  const int qA = tid >> 5;
  const int scg = (tid & 7) << 2;
  const int sr  = tid >> 3;

  f32x4 acc[4][2];
  #pragma unroll
  for (int i=0;i<4;i++)
    #pragma unroll
    for (int j=0;j<2;j++) acc[i][j] = f32x4{0.f,0.f,0.f,0.f};

  for (int k0=0; k0<256; k0+=32){
    __syncthreads();
    const float* sbase = &S[((size_t)bb*256 + k0 + cA)*4096 + p0];
    #pragma unroll
    for (int ps=0; ps<4; ps++){
      const int p = ps*32 + qA*4;
      const float4 f4 = *(const float4*)(sbase + p);
      As[p+0][cA] = (__bf16)f4.x;
      As[p+1][cA] = (__bf16)f4.y;
      As[p+2][cA] = (__bf16)f4.z;
      As[p+3][cA] = (__bf16)f4.w;
    }
    #pragma unroll
    for (int i=0;i<2;i++){
      const int row = sr + i*32;
      const float4 a4 = *(const float4*)&W[(size_t)(n0+row)*256 + k0 + scg];
      bf16x4 h; h[0]=(__bf16)a4.x; h[1]=(__bf16)a4.y; h[2]=(__bf16)a4.z; h[3]=(__bf16)a4.w;
      *(bf16x4*)&Bs[row][scg] = h;
    }
    __syncthreads();
    bf16x8 af[4], bfr[2];
    #pragma unroll
    for (int i=0;i<4;i++) af[i]  = *(const bf16x8*)&As[wr*64 + i*16 + lq][lk8];
    #pragma unroll
    for (int j=0;j<2;j++) bfr[j] = *(const bf16x8*)&Bs[wc*32 + j*16 + lq][lk8];
    #pragma unroll
    for (int i=0;i<4;i++)
      #pragma unroll
      for (int j=0;j<2;j++)
        acc[i][j] = MFMA16(af[i], bfr[j], acc[i][j]);
  }

  #pragma unroll
  for (int i=0;i<4;i++)
    #pragma unroll
    for (int j=0;j<2;j++){
      const int coln = n0 + wc*32 + j*16 + lq;
      const float bv = bias ? bias[coln] : 0.f;
      if (TRANSOUT){
        bf16x4 hv;
        #pragma unroll
        for (int r=0;r<4;r++) hv[r] = (__bf16)(acc[i][j][r] + bv);
        *(bf16x4*)&C[((size_t)bb*256 + coln)*4096 + p0 + wr*64 + i*16 + rb] = hv;
      } else {
        #pragma unroll
        for (int r=0;r<4;r++){
          const int rowm = m0 + wr*64 + i*16 + rb + r;
          C[(size_t)rowm*256 + coln] = (__bf16)(acc[i][j][r] + bv);
        }
      }
    }
}

// ---------------------------------------------------------------------------
__global__ __launch_bounds__(256) void add_vec4(const float* __restrict__ a,
                                                const float* __restrict__ b,
                                                float* __restrict__ o, int n4)
{
  const int i = blockIdx.x*blockDim.x + threadIdx.x;
  if (i < n4){
    const float4 x = ((const float4*)a)[i];
    const float4 y = ((const float4*)b)[i];
    float4 z; z.x=x.x+y.x; z.y=x.y+y.y; z.z=x.z+y.z; z.w=x.w+y.w;
    ((float4*)o)[i] = z;
  }
}

// ---------------------------------------------------------------------------
__global__ __launch_bounds__(256) void ln_kernel(const float* __restrict__ res,
                                                 const float* __restrict__ x,
                                                 const float* __restrict__ g,
                                                 const float* __restrict__ beta,
                                                 float* __restrict__ out)
{
  const int row  = blockIdx.x*4 + (threadIdx.x >> 6);
  const int lane = threadIdx.x & 63;
  const int c = lane*4;
  const float4 rv = *(const float4*)&res[(size_t)row*256 + c];
  const float4 xv = *(const float4*)&x[(size_t)row*256 + c];
  float v0=rv.x+xv.x, v1=rv.y+xv.y, v2=rv.z+xv.z, v3=rv.w+xv.w;
  float s = v0+v1+v2+v3;
  #pragma unroll
  for (int off=1; off<64; off<<=1) s += __shfl_xor(s, off);
  const float mean = s * (1.f/256.f);
  const float d0=v0-mean, d1=v1-mean, d2=v2-mean, d3=v3-mean;
  float q = d0*d0 + d1*d1 + d2*d2 + d3*d3;
  #pragma unroll
  for (int off=1; off<64; off<<=1) q += __shfl_xor(q, off);
  const float rstd = rsqrtf(q*(1.f/256.f) + 1e-5f);
  const float4 gv = *(const float4*)&g[c];
  const float4 bv = *(const float4*)&beta[c];
  float4 ov;
  ov.x = d0*rstd*gv.x + bv.x;
  ov.y = d1*rstd*gv.y + bv.y;
  ov.z = d2*rstd*gv.z + bv.z;
  ov.w = d3*rstd*gv.w + bv.w;
  *(float4*)&out[(size_t)row*256 + c] = ov;
}

// ---------------------------------------------------------------------------
// Flash self-attention, swapped-operand, zero-LDS.
// qs: bf16 [8192][256] (pre-scaled q); ks: bf16 [8192][256];
// vts: bf16 [8][256 d][1024 key] (pre-transposed V).
// Block = (qtile 64, b*8+h); 4 waves x 16 q-rows; KVBLK=64; DH=32.
// Each lane owns one q-row; P redistributed to B-frag layout via shfl.
// ---------------------------------------------------------------------------
__global__ __launch_bounds__(256) void flash_self(
    const __bf16* __restrict__ qs, const __bf16* __restrict__ ks,
    const __bf16* __restrict__ vts, float* __restrict__ sa)
{
  const int qt = blockIdx.x;
  const int b  = blockIdx.y >> 3;
  const int h  = blockIdx.y & 7;
  const int tid  = threadIdx.x;
  const int wid  = tid >> 6;
  const int lane = tid & 63;
  const int lq   = lane & 15;
  const int hi   = lane >> 4;
  const int lk8  = hi << 3;
  const int rb   = hi << 2;

  const int qrow = b*1024 + qt*64 + wid*16 + lq;
  const bf16x8 qf = *(const bf16x8*)&qs[(size_t)qrow*256 + h*32 + lk8];

  const __bf16* kb0 = &ks[(size_t)(b*1024 + lq)*256 + h*32 + lk8];
  const __bf16* vb0 = &vts[(size_t)(b*256 + h*32 + lq)*1024 + lk8];

  const f32x4 Z = {0.f, 0.f, 0.f, 0.f};
  float m = -1e30f, l = 0.f;
  f32x4 o0 = Z, o1 = Z;

  for (int it=0; it<16; ++it){
    const int key0 = it*64;
    // S^T = K · Q^T : s4[kt][r] = S[key = key0+kt*16+rb+r][q = lq]
    f32x4 s4[4];
    #pragma unroll
    for (int kt=0;kt<4;kt++){
      const bf16x8 kf = *(const bf16x8*)(kb0 + (size_t)(key0 + kt*16)*256);
      s4[kt] = MFMA16(kf, qf, Z);
    }
    float pm = s4[0][0];
    #pragma unroll
    for (int kt=0;kt<4;kt++)
      #pragma unroll
      for (int r=0;r<4;r++) pm = fmaxf(pm, s4[kt][r]);
    pm = fmaxf(pm, __shfl_xor(pm,16));
    pm = fmaxf(pm, __shfl_xor(pm,32));
    if (!__all(pm <= m + 8.f)){   // defer-max (T13)
      const float mn = fmaxf(m, pm);
      const float alpha = __expf(m - mn);
      o0[0]*=alpha; o0[1]*=alpha; o0[2]*=alpha; o0[3]*=alpha;
      o1[0]*=alpha; o1[1]*=alpha; o1[2]*=alpha; o1[3]*=alpha;
      l *= alpha;
      m = mn;
    }
    float p[4][4]; float rs = 0.f;
    #pragma unroll
    for (int kt=0;kt<4;kt++)
      #pragma unroll
      for (int r=0;r<4;r++){ p[kt][r] = __expf(s4[kt][r]-m); rs += p[kt][r]; }
    rs += __shfl_xor(rs,16);
    rs += __shfl_xor(rs,32);
    l += rs;
    // redistribute P to PV B-frag layout (verified pattern from flash_cross)
    unsigned pk0[4], pk1[4];
    #pragma unroll
    for (int kt=0;kt<4;kt++){
      pk0[kt] = pack2bf(p[kt][0], p[kt][1]);
      pk1[kt] = pack2bf(p[kt][2], p[kt][3]);
    }
    const int srcA = ((hi&1)<<5) + lq;
    const int srcB = srcA + 16;
    const bool ksel = hi >= 2;
    bf16x8 pf[2];
    #pragma unroll
    for (int ks2=0; ks2<2; ks2++){
      const unsigned a0 = (unsigned)__shfl((int)pk0[2*ks2],   srcA);
      const unsigned a1 = (unsigned)__shfl((int)pk0[2*ks2+1], srcA);
      const unsigned b0 = (unsigned)__shfl((int)pk1[2*ks2],   srcA);
      const unsigned b1 = (unsigned)__shfl((int)pk1[2*ks2+1], srcA);
      const unsigned c0 = (unsigned)__shfl((int)pk0[2*ks2],   srcB);
      const unsigned c1 = (unsigned)__shfl((int)pk0[2*ks2+1], srcB);
      const unsigned d0 = (unsigned)__shfl((int)pk1[2*ks2],   srcB);
      const unsigned d1 = (unsigned)__shfl((int)pk1[2*ks2+1], srcB);
      union { unsigned u[4]; bf16x8 v; } uu;
      uu.u[0] = ksel ? a1 : a0;
      uu.u[1] = ksel ? b1 : b0;
      uu.u[2] = ksel ? c1 : c0;
      uu.u[3] = ksel ? d1 : d0;
      pf[ks2] = uu.v;
    }
    // O^T += V^T · P^T
    #pragma unroll
    for (int ks2=0; ks2<2; ks2++){
      const bf16x8 vf0 = *(const bf16x8*)(vb0 + key0 + ks2*32);
      const bf16x8 vf1 = *(const bf16x8*)(vb0 + (size_t)16*1024 + key0 + ks2*32);
      o0 = MFMA16(vf0, pf[ks2], o0);
      o1 = MFMA16(vf1, pf[ks2], o1);
    }
  }
  const float inv = 1.f / l;
  f32x4 w0, w1;
  #pragma unroll
  for (int r=0;r<4;r++){ w0[r] = o0[r]*inv; w1[r] = o1[r]*inv; }
  *(f32x4*)&sa[(size_t)qrow*256 + h*32 + rb]      = w0;
  *(f32x4*)&sa[(size_t)qrow*256 + h*32 + 16 + rb] = w1;
}

// ---------------------------------------------------------------------------
// Flash cross-attention (unchanged, verified in round 2).
// ---------------------------------------------------------------------------
__global__ __launch_bounds__(256, 2) void flash_cross(
    const __bf16* __restrict__ qg, const __bf16* __restrict__ kg,
    const __bf16* __restrict__ vtg, float* __restrict__ Opart,
    float* __restrict__ ml)
{
  extern __shared__ __bf16 smem[];
  __bf16* Ks = smem;            // [64][256]
  __bf16* Vt = smem + 64*256;   // [256][64]

  const int qt = blockIdx.x;
  const int b  = blockIdx.y;
  const int sl = blockIdx.z;
  const int tid  = threadIdx.x;
  const int wid  = tid >> 6;
  const int lane = tid & 63;
  const int lq   = lane & 15;
  const int hi   = lane >> 4;
  const int lk8  = hi << 3;
  const int rb   = hi << 2;
  const int swz  = lq & 7;

  const int qrow = b*1024 + qt*64 + wid*16 + lq;
  bf16x8 qf[8];
  #pragma unroll
  for (int ks=0; ks<8; ks++)
    qf[ks] = *(const bf16x8*)&qg[(size_t)qrow*256 + ks*32 + lk8];

  const f32x4 Z = {0.f, 0.f, 0.f, 0.f};
  float m = -1e30f, l = 0.f;
  f32x4 o[16];
  #pragma unroll
  for (int nf=0; nf<16; nf++) o[nf] = Z;

  const int srow = tid >> 2;
  const int sc4  = tid & 3;

  for (int it=0; it<16; ++it){
    const int key0 = sl*1024 + it*64;
    __syncthreads();
    {
      const __bf16* kb = &kg[(size_t)(b*4096 + key0 + srow)*256];
      #pragma unroll
      for (int j=0;j<8;j++){
        const int ch = sc4 + j*4;
        const bf16x8 vv = *(const bf16x8*)(kb + ch*8);
        *(bf16x8*)&Ks[srow*256 + ((ch ^ (srow&7))<<3)] = vv;
      }
    }
    {
      #pragma unroll
      for (int ps=0; ps<4; ps++){
        const int d = srow + ps*64;
        const __bf16* vb = &vtg[(size_t)(b*256 + d)*4096 + key0];
        #pragma unroll
        for (int s2=0;s2<2;s2++){
          const int ch = sc4 + s2*4;
          const bf16x8 vv = *(const bf16x8*)(vb + ch*8);
          *(bf16x8*)&Vt[d*64 + ((ch ^ (d&7))<<3)] = vv;
        }
      }
    }
    __syncthreads();
    f32x4 s4[4];
    #pragma unroll
    for (int kt=0;kt<4;kt++) s4[kt] = Z;
    #pragma unroll
    for (int ks=0; ks<8; ks++){
      #pragma unroll
      for (int kt=0; kt<4; kt++){
        const bf16x8 kf = *(const bf16x8*)&Ks[(kt*16+lq)*256 + (((ks*4+hi) ^ swz)<<3)];
        s4[kt] = MFMA16(kf, qf[ks], s4[kt]);
      }
    }
    float pm = s4[0][0];
    #pragma unroll
    for (int kt=0;kt<4;kt++)
      #pragma unroll
      for (int r=0;r<4;r++) pm = fmaxf(pm, s4[kt][r]);
    pm = fmaxf(pm, __shfl_xor(pm, 16));
    pm = fmaxf(pm, __shfl_xor(pm, 32));
    if (!__all(pm <= m + 8.f)){
      const float mn = fmaxf(m, pm);
      const float alpha = __expf(m - mn);
      #pragma unroll
      for (int nf=0;nf<16;nf++){
        o[nf][0]*=alpha; o[nf][1]*=alpha; o[nf][2]*=alpha; o[nf][3]*=alpha;
      }
      l *= alpha;
      m = mn;
    }
    float p[4][4];
    float rs = 0.f;
    #pragma unroll
    for (int kt=0;kt<4;kt++)
      #pragma unroll
      for (int r=0;r<4;r++){ p[kt][r] = __expf(s4[kt][r] - m); rs += p[kt][r]; }
    rs += __shfl_xor(rs, 16);
    rs += __shfl_xor(rs, 32);
    l += rs;
    unsigned pk0[4], pk1[4];
    #pragma unroll
    for (int kt=0;kt<4;kt++){
      pk0[kt] = pack2bf(p[kt][0], p[kt][1]);
      pk1[kt] = pack2bf(p[kt][2], p[kt][3]);
    }
    const int srcA = ((hi&1)<<5) + lq;
    const int srcB = srcA + 16;
    const bool ksel = hi >= 2;
    bf16x8 pf[2];
    #pragma unroll
    for (int ks2=0; ks2<2; ks2++){
      const unsigned a0 = (unsigned)__shfl((int)pk0[2*ks2],   srcA);
      const unsigned a1 = (unsigned)__shfl((int)pk0[2*ks2+1], srcA);
      const unsigned b0 = (unsigned)__shfl((int)pk1[2*ks2],   srcA);
      const unsigned b1 = (unsigned)__shfl((int)pk1[2*ks2+1], srcA);
      const unsigned c0 = (unsigned)__shfl((int)pk0[2*ks2],   srcB);
      const unsigned c1 = (unsigned)__shfl((int)pk0[2*ks2+1], srcB);
      const unsigned d0 = (unsigned)__shfl((int)pk1[2*ks2],   srcB);
      const unsigned d1 = (unsigned)__shfl((int)pk1[2*ks2+1], srcB);
      union { unsigned u[4]; bf16x8 v; } uu;
      uu.u[0] = ksel ? a1 : a0;
      uu.u[1] = ksel ? b1 : b0;
      uu.u[2] = ksel ? c1 : c0;
      uu.u[3] = ksel ? d1 : d0;
      pf[ks2] = uu.v;
    }
    #pragma unroll
    for (int nf=0; nf<16; nf++){
      #pragma unroll
      for (int ks2=0; ks2<2; ks2++){
        const bf16x8 af = *(const bf16x8*)&Vt[(nf*16+lq)*64 + (((ks2*4+hi) ^ swz)<<3)];
        o[nf] = MFMA16(af, pf[ks2], o[nf]);
      }
    }
  }
  const int row = b*1024 + qt*64 + wid*16 + lq;
  if (hi == 0){
    ml[(size_t)(sl*8192 + row)*2 + 0] = m;
    ml[(size_t)(sl*8192 + row)*2 + 1] = l;
  }
  #pragma unroll
  for (int nf=0; nf<16; nf++)
    *(f32x4*)&Opart[(size_t)(sl*8192 + row)*256 + nf*16 + rb] = o[nf];
}

// ---------------------------------------------------------------------------
__global__ __launch_bounds__(256) void combine_kernel(const float* __restrict__ Opart,
                                                      const float* __restrict__ ml,
                                                      float* __restrict__ out)
{
  const int row = blockIdx.x;
  const int d = threadIdx.x;
  float mm[4], ll[4];
  #pragma unroll
  for (int s=0;s<4;s++){
    mm[s] = ml[(size_t)(s*8192+row)*2 + 0];
    ll[s] = ml[(size_t)(s*8192+row)*2 + 1];
  }
  const float M = fmaxf(fmaxf(mm[0],mm[1]), fmaxf(mm[2],mm[3]));
  float L = 0.f, acc = 0.f;
  #pragma unroll
  for (int s=0;s<4;s++){
    const float e = __expf(mm[s]-M);
    L   += ll[s]*e;
    acc += e * Opart[(size_t)(s*8192+row)*256 + d];
  }
  out[(size_t)row*256 + d] = acc / L;
}

// ---------------------------------------------------------------------------
extern "C" void kernel_launch(void* const* d_in, const int* in_sizes, int n_in,
                              void* d_out, int out_size, void* d_ws, size_t ws_size,
                              hipStream_t stream)
{
  (void)in_sizes; (void)n_in; (void)out_size; (void)ws_size;
  const float* tgt        = (const float*)d_in[0];
  const float* srcs       = (const float*)d_in[2];
  const float* posemb     = (const float*)d_in[3];
  const float* in_proj_w  = (const float*)d_in[4];
  const float* in_proj_b  = (const float*)d_in[5];
  const float* out_proj_w = (const float*)d_in[6];
  const float* out_proj_b = (const float*)d_in[7];
  const float* lin_q_w    = (const float*)d_in[8];
  const float* lin_q_b    = (const float*)d_in[9];
  const float* lin_k_w    = (const float*)d_in[10];
  const float* lin_k_b    = (const float*)d_in[11];
  const float* lin_v_w    = (const float*)d_in[12];
  const float* lin_v_b    = (const float*)d_in[13];
  const float* lin_o_w    = (const float*)d_in[14];
  const float* lin_o_b    = (const float*)d_in[15];
  const float* norm1_g    = (const float*)d_in[16];
  const float* norm1_b    = (const float*)d_in[17];
  const float* norm2_g    = (const float*)d_in[18];
  const float* norm2_b    = (const float*)d_in[19];
  const float* ffn_w1     = (const float*)d_in[20];
  const float* ffn_b1     = (const float*)d_in[21];
  const float* ffn_w2     = (const float*)d_in[22];
  const float* ffn_b2     = (const float*)d_in[23];
  const float* ffn_norm_g = (const float*)d_in[24];
  const float* ffn_norm_b = (const float*)d_in[25];
  float* out = (float*)d_out;

  char* w = (char*)d_ws;
  const size_t MB = (size_t)1 << 20;
  // Region plan, peak 82.25 MB:
  //  @0   tgt1 (8MB, steps 7..14)
  //  @8   qk(1-3) -> sa(5-6) -> query_b(8-11) -> attn2(12-13) -> ffn_out(16-17)
  //  @16  q_s(2-5,4MB) ; then key_b(9-11,16MB) ; then t2proj(13-14,8MB)
  //  @20  k_s(3-5,4MB)   [inside key_b region after q_s/k_s dead]
  //  @24  v_t(4-5,4MB) ; then tgt3(14..17,8MB)
  //  @28  saproj(6-7,8MB)
  //  @32  val_t(10-11,16MB) ; then ffn_h(15-16,32MB @32..64)
  //  @48  Opart(11-12,32MB @48..80)   [val_t dead by combine]
  //  @82  ml (256KB)
  float*  tgt1    = (float*)(w + 0);
  float*  qk      = (float*)(w + 8*MB);
  float*  sa      = (float*)(w + 8*MB);
  __bf16* query_b = (__bf16*)(w + 8*MB);
  float*  attn2   = (float*)(w + 8*MB);
  float*  ffn_out = (float*)(w + 8*MB);
  __bf16* q_s     = (__bf16*)(w + 16*MB);
  __bf16* key_b   = (__bf16*)(w + 16*MB);
  float*  t2proj  = (float*)(w + 16*MB);
  __bf16* k_s     = (__bf16*)(w + 20*MB);
  __bf16* v_t     = (__bf16*)(w + 24*MB);
  float*  tgt3    = (float*)(w + 24*MB);
  float*  saproj  = (float*)(w + 28*MB);
  __bf16* val_t   = (__bf16*)(w + 32*MB);
  float*  ffn_h   = (float*)(w + 32*MB);
  float*  Opart   = (float*)(w + 48*MB);
  float*  ml      = (float*)(w + 82*MB);

  const float SCALE = 0.17677669529663687f;  // 1/sqrt(32)

  // ---- Stage A: self-attention ----
  add_vec4<<<2048,256,0,stream>>>(tgt, posemb, qk, (8*1024*256)/4);
  gemm_bt<64,false,1><<<dim3(128,4),256,0,stream>>>(qk, in_proj_w, in_proj_b,
      q_s, 8192,256,256, 256,0, SCALE);
  gemm_bt<64,false,1><<<dim3(128,4),256,0,stream>>>(qk, in_proj_w + 256*256,
      in_proj_b + 256, k_s, 8192,256,256, 256,0, 1.f);
  gemm_bt<64,false,2><<<dim3(128,4),256,0,stream>>>(tgt, in_proj_w + 512*256,
      in_proj_b + 512, v_t, 8192,256,256, 256,0, 1.f);
  flash_self<<<dim3(16,64),256,0,stream>>>(q_s, k_s, v_t, sa);
  gemm_bt<64,false,0><<<dim3(128,4),256,0,stream>>>(sa, out_proj_w, out_proj_b,
      saproj, 8192,256,256, 256,0, 1.f);
  ln_kernel<<<2048,256,0,stream>>>(tgt, saproj, norm2_g, norm2_b, tgt1);

  // ---- Stage B: cross-attention ----
  gemm_bt<64,false,1><<<dim3(128,4),256,0,stream>>>(tgt1, lin_q_w, lin_q_b,
      query_b, 8192,256,256, 256,0, 1.f);
  gemm_srcs<false><<<dim3(256,4),256,0,stream>>>(srcs, lin_k_w, lin_k_b, key_b);
  gemm_srcs<true ><<<dim3(256,4),256,0,stream>>>(srcs, lin_v_w, lin_v_b, val_t);
  flash_cross<<<dim3(16,8,4),256,65536,stream>>>(query_b, key_b, val_t, Opart, ml);
  combine_kernel<<<8192,256,0,stream>>>(Opart, ml, attn2);
  gemm_bt<64,false,0><<<dim3(128,4),256,0,stream>>>(attn2, lin_o_w, lin_o_b,
      t2proj, 8192,256,256, 256,0, 1.f);
  ln_kernel<<<2048,256,0,stream>>>(tgt1, t2proj, norm1_g, norm1_b, tgt3);

  // ---- Stage C: FFN ----
  gemm_bt<128,true,0><<<dim3(64,16),256,0,stream>>>(tgt3, ffn_w1, ffn_b1,
      ffn_h, 8192,1024,256, 1024,0, 1.f);
  gemm_bt<64,false,0><<<dim3(128,4),256,0,stream>>>(ffn_h, ffn_w2, ffn_b2,
      ffn_out, 8192,256,1024, 256,0, 1.f);
  ln_kernel<<<2048,256,0,stream>>>(tgt3, ffn_out, ffn_norm_g, ffn_norm_b, out);
}